// Round 10
// baseline (61.548 us; speedup 1.0000x reference)
//
#include <hip/hip_runtime.h>
#include <cstdint>

#define EMBED      2048
#define NEXP       16
#define NWAVES     8                   // d-split waves per block
#define TOKB       64                  // tokens per block
#define DPW        256                 // d per wave
#define NTOK_TOTAL (8 * 4096)
#define WOFF       (NTOK_TOTAL * 2)    // float offset of indices region in d_out
#define PAD        17                  // part row pad (conflict-free)

typedef float f32x4 __attribute__((ext_vector_type(4)));

// nontemporal float4 load: emits global_load_dwordx4 ... nt (stream x without
// cache-retention / Infinity-Cache churn). SINGLE CHANGE vs R9.
__device__ __forceinline__ float4 ldnt4(const float* p) {
    const f32x4 v = __builtin_nontemporal_load((const f32x4*)p);
    return make_float4(v.x, v.y, v.z, v.w);
}

// DPP quad_perm xor swaps (pure VALU, no LDS pipe)
__device__ __forceinline__ float dpp_xor1(float v) {
    return __builtin_bit_cast(float,
        __builtin_amdgcn_mov_dpp(__builtin_bit_cast(int, v), 0xB1, 0xF, 0xF, false));
}
__device__ __forceinline__ float dpp_xor2(float v) {
    return __builtin_bit_cast(float,
        __builtin_amdgcn_mov_dpp(__builtin_bit_cast(int, v), 0x4E, 0xF, 0xF, false));
}
// ds_swizzle BitMode xor within 32-lane halves (imm = xor<<10 | 0x1F)
template <int IMM>
__device__ __forceinline__ float swz(float v) {
    return __builtin_bit_cast(float,
        __builtin_amdgcn_ds_swizzle(__builtin_bit_cast(int, v), IMM));
}

// R9 structure (W-in-VGPR, coalesced direct x loads, barrier-free butterfly
// fold) with NONTEMPORAL x loads — the discriminating probe for whether the
// 4.5 TB/s convergence (R4/R6/R9 all ~59us) is Infinity-Cache churn (268MB
// footprint marginally exceeds the 256MB L3) or the honest read ceiling.
extern "C" __global__ __launch_bounds__(NWAVES * 64, 4)
void router_kernel(const float* __restrict__ x,
                   const float* __restrict__ gw,
                   float* __restrict__ out)
{
    __shared__ float part[NWAVES][TOKB][PAD];   // 34.8 KB -> 2 blocks/CU

    const int tid  = threadIdx.x;
    const int lane = tid & 63;
    const int w    = __builtin_amdgcn_readfirstlane(tid >> 6);
    const int t0   = blockIdx.x * TOKB;

    // ---- W preload: 16 experts x this lane's 4-d slice = 64 VGPRs ----
    float4 Wr[NEXP];
#pragma unroll
    for (int e = 0; e < NEXP; ++e)
        Wr[e] = *(const float4*)(gw + (size_t)e * EMBED + w * DPW + lane * 4);

    const float* xb = x + (size_t)t0 * EMBED + w * DPW + lane * 4;
    const bool b1 = lane & 1, b2 = lane & 2, b4 = lane & 4, b8 = lane & 8;

    auto proc = [&](int t, float4 x4) {
        float a[NEXP];
#pragma unroll
        for (int e = 0; e < NEXP; ++e) {
            a[e] = x4.x * Wr[e].x;
            a[e] = fmaf(x4.y, Wr[e].y, a[e]);
            a[e] = fmaf(x4.z, Wr[e].z, a[e]);
            a[e] = fmaf(x4.w, Wr[e].w, a[e]);
        }
        // fold 16 values over 64 lanes; keep/give butterfly
#pragma unroll
        for (int i = 0; i < 8; ++i) {              // xor1: 16 -> 8
            const float keep = b1 ? a[i + 8] : a[i];
            const float give = b1 ? a[i] : a[i + 8];
            a[i] = keep + dpp_xor1(give);
        }
#pragma unroll
        for (int i = 0; i < 4; ++i) {              // xor2: 8 -> 4
            const float keep = b2 ? a[i + 4] : a[i];
            const float give = b2 ? a[i] : a[i + 4];
            a[i] = keep + dpp_xor2(give);
        }
#pragma unroll
        for (int i = 0; i < 2; ++i) {              // xor4: 4 -> 2
            const float keep = b4 ? a[i + 2] : a[i];
            const float give = b4 ? a[i] : a[i + 2];
            a[i] = keep + swz<0x101F>(give);
        }
        {                                          // xor8: 2 -> 1
            const float keep = b8 ? a[1] : a[0];
            const float give = b8 ? a[0] : a[1];
            a[0] = keep + swz<0x201F>(give);
        }
        a[0] += swz<0x401F>(a[0]);                 // xor16
        a[0] += __shfl_xor(a[0], 32, 64);          // xor32
        if (lane < NEXP) part[w][t][lane] = a[0];  // 16 consecutive banks
    };

    // ---- main loop: 4-token register prefetch ring, no barriers ----
    float4 xp0 = ldnt4(xb + (size_t)0 * EMBED);
    float4 xp1 = ldnt4(xb + (size_t)1 * EMBED);
    float4 xp2 = ldnt4(xb + (size_t)2 * EMBED);
    float4 xp3 = ldnt4(xb + (size_t)3 * EMBED);
    for (int t = 0; t < TOKB - 4; t += 4) {
        proc(t + 0, xp0); xp0 = ldnt4(xb + (size_t)(t + 4) * EMBED);
        proc(t + 1, xp1); xp1 = ldnt4(xb + (size_t)(t + 5) * EMBED);
        proc(t + 2, xp2); xp2 = ldnt4(xb + (size_t)(t + 6) * EMBED);
        proc(t + 3, xp3); xp3 = ldnt4(xb + (size_t)(t + 7) * EMBED);
    }
    proc(TOKB - 4, xp0);
    proc(TOKB - 3, xp1);
    proc(TOKB - 2, xp2);
    proc(TOKB - 1, xp3);

    __syncthreads();

    // ---- finalize (bitrev4 slot->expert permutation folded in) ----
    if (tid < TOKB) {
        constexpr int SIG[NEXP] = {0, 8, 4, 12, 2, 10, 6, 14,
                                   1, 9, 5, 13, 3, 11, 7, 15};
        float tot[NEXP];
#pragma unroll
        for (int e = 0; e < NEXP; ++e) tot[e] = 0.0f;
#pragma unroll
        for (int wv = 0; wv < NWAVES; ++wv) {
#pragma unroll
            for (int j = 0; j < NEXP; ++j) tot[SIG[j]] += part[wv][tid][j];
        }

        // top-2 with lowest-index tie-break (strict >), matches lax.top_k
        float m1 = tot[0]; int i1 = 0;
#pragma unroll
        for (int e = 1; e < NEXP; ++e) {
            if (tot[e] > m1) { m1 = tot[e]; i1 = e; }
        }
        float m2 = -INFINITY; int i2 = 0;
#pragma unroll
        for (int e = 0; e < NEXP; ++e) {
            const bool sel = (e != i1) && (tot[e] > m2);
            if (sel) { m2 = tot[e]; i2 = e; }
        }

        // normalized top-2 weights = softmax over the two logits
        const float ed = __expf(m2 - m1);   // <= 1
        const float w1 = 1.0f / (1.0f + ed);
        const float w2 = 1.0f - w1;

        const int t = t0 + tid;
        out[t * 2 + 0] = w1;
        out[t * 2 + 1] = w2;
        out[WOFF + t * 2 + 0] = (float)i1;
        out[WOFF + t * 2 + 1] = (float)i2;
    }
}

extern "C" void kernel_launch(void* const* d_in, const int* in_sizes, int n_in,
                              void* d_out, int out_size, void* d_ws, size_t ws_size,
                              hipStream_t stream) {
    const float* x  = (const float*)d_in[0];   // [8,4096,2048] f32
    const float* gw = (const float*)d_in[1];   // [16,2048] f32
    float* out = (float*)d_out;                // weights[65536] ++ indices-as-f32[65536]

    const int nblocks = NTOK_TOTAL / TOKB;     // 512 blocks x 512 threads
    router_kernel<<<dim3(nblocks), dim3(NWAVES * 64), 0, stream>>>(x, gw, out);
}

// Round 11
// 58.596 us; speedup vs baseline: 1.0504x; 1.0504x over previous
//
#include <hip/hip_runtime.h>
#include <cstdint>

#define EMBED      2048
#define NEXP       16
#define NWAVES     8                   // d-split waves per block
#define TOKB       64                  // tokens per block
#define DPW        256                 // d per wave
#define NTOK_TOTAL (8 * 4096)
#define WOFF       (NTOK_TOTAL * 2)    // float offset of indices region in d_out
#define PAD        17                  // part row pad (conflict-free)

// DPP quad_perm xor swaps (pure VALU, no LDS pipe)
__device__ __forceinline__ float dpp_xor1(float v) {
    return __builtin_bit_cast(float,
        __builtin_amdgcn_mov_dpp(__builtin_bit_cast(int, v), 0xB1, 0xF, 0xF, false));
}
__device__ __forceinline__ float dpp_xor2(float v) {
    return __builtin_bit_cast(float,
        __builtin_amdgcn_mov_dpp(__builtin_bit_cast(int, v), 0x4E, 0xF, 0xF, false));
}
// ds_swizzle BitMode xor within 32-lane halves (imm = xor<<10 | 0x1F)
template <int IMM>
__device__ __forceinline__ float swz(float v) {
    return __builtin_bit_cast(float,
        __builtin_amdgcn_ds_swizzle(__builtin_bit_cast(int, v), IMM));
}

// FINAL (= R9, best measured 58.8us): W-in-VGPR router.
//  wave = 256-d slice, lane = 4 consecutive d.
//  - W[e][lane's 4 d] preloaded once: 64 VGPRs. Zero W traffic in the loop.
//  - x: ONE perfectly-coalesced float4 wave-load per (wave, token); no LDS
//    staging, no barriers in the main loop; 4-slot register prefetch ring.
//  - per token: 64 fmaf -> butterfly fold (DPP xor1/2, ds_swizzle xor4/8/16,
//    shfl xor32) -> lane j<16 holds expert bitrev4(j)'s 256-d partial.
//  - one sparse LDS write per (wave, token); single barrier; finalize folds
//    the bitrev4 permutation in at compile time.
// Measured ceiling: 268 MB mandatory x stream at ~4.55 TB/s effective
// read-service rate (R4/R6/R9 convergence) = 58.9us floor; R9 = 58.8us.
extern "C" __global__ __launch_bounds__(NWAVES * 64, 4)
void router_kernel(const float* __restrict__ x,
                   const float* __restrict__ gw,
                   float* __restrict__ out)
{
    __shared__ float part[NWAVES][TOKB][PAD];   // 34.8 KB -> 2 blocks/CU

    const int tid  = threadIdx.x;
    const int lane = tid & 63;
    const int w    = __builtin_amdgcn_readfirstlane(tid >> 6);
    const int t0   = blockIdx.x * TOKB;

    // ---- W preload: 16 experts x this lane's 4-d slice = 64 VGPRs ----
    float4 Wr[NEXP];
#pragma unroll
    for (int e = 0; e < NEXP; ++e)
        Wr[e] = *(const float4*)(gw + (size_t)e * EMBED + w * DPW + lane * 4);

    const float* xb = x + (size_t)t0 * EMBED + w * DPW + lane * 4;
    const bool b1 = lane & 1, b2 = lane & 2, b4 = lane & 4, b8 = lane & 8;

    auto proc = [&](int t, float4 x4) {
        float a[NEXP];
#pragma unroll
        for (int e = 0; e < NEXP; ++e) {
            a[e] = x4.x * Wr[e].x;
            a[e] = fmaf(x4.y, Wr[e].y, a[e]);
            a[e] = fmaf(x4.z, Wr[e].z, a[e]);
            a[e] = fmaf(x4.w, Wr[e].w, a[e]);
        }
        // fold 16 values over 64 lanes; keep/give butterfly
#pragma unroll
        for (int i = 0; i < 8; ++i) {              // xor1: 16 -> 8
            const float keep = b1 ? a[i + 8] : a[i];
            const float give = b1 ? a[i] : a[i + 8];
            a[i] = keep + dpp_xor1(give);
        }
#pragma unroll
        for (int i = 0; i < 4; ++i) {              // xor2: 8 -> 4
            const float keep = b2 ? a[i + 4] : a[i];
            const float give = b2 ? a[i] : a[i + 4];
            a[i] = keep + dpp_xor2(give);
        }
#pragma unroll
        for (int i = 0; i < 2; ++i) {              // xor4: 4 -> 2
            const float keep = b4 ? a[i + 2] : a[i];
            const float give = b4 ? a[i] : a[i + 2];
            a[i] = keep + swz<0x101F>(give);
        }
        {                                          // xor8: 2 -> 1
            const float keep = b8 ? a[1] : a[0];
            const float give = b8 ? a[0] : a[1];
            a[0] = keep + swz<0x201F>(give);
        }
        a[0] += swz<0x401F>(a[0]);                 // xor16
        a[0] += __shfl_xor(a[0], 32, 64);          // xor32
        if (lane < NEXP) part[w][t][lane] = a[0];  // 16 consecutive banks
    };

    // ---- main loop: 4-token register prefetch ring, no barriers ----
    float4 xp0 = *(const float4*)(xb + (size_t)0 * EMBED);
    float4 xp1 = *(const float4*)(xb + (size_t)1 * EMBED);
    float4 xp2 = *(const float4*)(xb + (size_t)2 * EMBED);
    float4 xp3 = *(const float4*)(xb + (size_t)3 * EMBED);
    for (int t = 0; t < TOKB - 4; t += 4) {
        proc(t + 0, xp0); xp0 = *(const float4*)(xb + (size_t)(t + 4) * EMBED);
        proc(t + 1, xp1); xp1 = *(const float4*)(xb + (size_t)(t + 5) * EMBED);
        proc(t + 2, xp2); xp2 = *(const float4*)(xb + (size_t)(t + 6) * EMBED);
        proc(t + 3, xp3); xp3 = *(const float4*)(xb + (size_t)(t + 7) * EMBED);
    }
    proc(TOKB - 4, xp0);
    proc(TOKB - 3, xp1);
    proc(TOKB - 2, xp2);
    proc(TOKB - 1, xp3);

    __syncthreads();

    // ---- finalize (bitrev4 slot->expert permutation folded in) ----
    if (tid < TOKB) {
        constexpr int SIG[NEXP] = {0, 8, 4, 12, 2, 10, 6, 14,
                                   1, 9, 5, 13, 3, 11, 7, 15};
        float tot[NEXP];
#pragma unroll
        for (int e = 0; e < NEXP; ++e) tot[e] = 0.0f;
#pragma unroll
        for (int wv = 0; wv < NWAVES; ++wv) {
#pragma unroll
            for (int j = 0; j < NEXP; ++j) tot[SIG[j]] += part[wv][tid][j];
        }

        // top-2 with lowest-index tie-break (strict >), matches lax.top_k
        float m1 = tot[0]; int i1 = 0;
#pragma unroll
        for (int e = 1; e < NEXP; ++e) {
            if (tot[e] > m1) { m1 = tot[e]; i1 = e; }
        }
        float m2 = -INFINITY; int i2 = 0;
#pragma unroll
        for (int e = 0; e < NEXP; ++e) {
            const bool sel = (e != i1) && (tot[e] > m2);
            if (sel) { m2 = tot[e]; i2 = e; }
        }

        // normalized top-2 weights = softmax over the two logits
        const float ed = __expf(m2 - m1);   // <= 1
        const float w1 = 1.0f / (1.0f + ed);
        const float w2 = 1.0f - w1;

        const int t = t0 + tid;
        out[t * 2 + 0] = w1;
        out[t * 2 + 1] = w2;
        out[WOFF + t * 2 + 0] = (float)i1;
        out[WOFF + t * 2 + 1] = (float)i2;
    }
}

extern "C" void kernel_launch(void* const* d_in, const int* in_sizes, int n_in,
                              void* d_out, int out_size, void* d_ws, size_t ws_size,
                              hipStream_t stream) {
    const float* x  = (const float*)d_in[0];   // [8,4096,2048] f32
    const float* gw = (const float*)d_in[1];   // [16,2048] f32
    float* out = (float*)d_out;                // weights[65536] ++ indices-as-f32[65536]

    const int nblocks = NTOK_TOTAL / TOKB;     // 512 blocks x 512 threads
    router_kernel<<<dim3(nblocks), dim3(NWAVES * 64), 0, stream>>>(x, gw, out);
}